// Round 8
// baseline (1136.352 us; speedup 1.0000x reference)
//
#include <hip/hip_runtime.h>
#include <math.h>

#define F 256
#define KMIX 5
#define RECB 640     // node record: 512 B bf16 xm + 32 B mask bits + 96 B pad
#define GR 16        // source-node groups (L2 locality phases)
#define GS 3136      // group size: 16*3136 = 50176 >= N; 3136*640 B = 2.0 MB per group

typedef __attribute__((ext_vector_type(8))) short bf16x8;
typedef __attribute__((ext_vector_type(4))) float f32x4;

__device__ __forceinline__ float bf2f(unsigned short u) {
  union { unsigned int i; float f; } v; v.i = ((unsigned int)u) << 16; return v.f;
}
__device__ __forceinline__ unsigned short f2bf(float f) {
  union { float f; unsigned int i; } v; v.f = f;
  unsigned int u = v.i;
  unsigned int r = (u + 0x7fffu + ((u >> 16) & 1u)) >> 16;
  return (unsigned short)r;
}

__device__ __forceinline__ f32x4 MFMA(bf16x8 a, bf16x8 b, f32x4 c) {
  return __builtin_amdgcn_mfma_f32_16x16x32_bf16(a, b, c, 0, 0, 0);
}

// Fast E[relu(N(mu,sigma))]: 0.5*mu + 0.5*(mu^2+c1*sig)*rsqrt(mu^2+2*c1*sig), c1=4/pi.
// Exact at w=0 and asymptotes; max abs err ~0.025*sqrt(sig). sigma==0 -> max(mu,0).
__device__ __forceinline__ float ex_relu_fast(float mu, float sig) {
  const float c1 = 1.2732395447f;
  const float c2 = 2.5464790895f;
  float t = mu * mu;
  float u = t + c1 * sig;
  float v = t + c2 * sig + 1e-20f;
  float r = __builtin_amdgcn_rsqf(v);
  return 0.5f * mu + 0.5f * u * r;
}

__global__ void kzero(unsigned int* p, long long n) {
  long long i = (long long)blockIdx.x * blockDim.x + threadIdx.x;
  long long stride = (long long)gridDim.x * blockDim.x;
  for (; i < n; i += stride) p[i] = 0u;
}

// ivar[k][f] = exp(-logvars[k][f])
__global__ __launch_bounds__(256) void k_tab(const float* __restrict__ logvars,
                                             float* __restrict__ ivar) {
  int i = blockIdx.x * 256 + threadIdx.x;
  if (i < KMIX * F) ivar[i] = __expf(-logvars[i]);
}

// Per-node: record = [bf16 xm | bit mask], gamma = softmax_k(logp - 0.5*sum diff2)
// (reference's -0.5*F*log(2pi) and -0.5*sum(logvars) are k-independent -> cancel)
__global__ __launch_bounds__(256) void k_prep(
    const float* __restrict__ x, const int* __restrict__ mask,
    const float* __restrict__ logp, const float* __restrict__ means,
    const float* __restrict__ ivar,
    unsigned char* __restrict__ rec, float* __restrict__ gamma, int Npad) {
  int n = blockIdx.x;
  int f = threadIdx.x;
  int idx = n * F + f;
  float xv = x[idx];
  int m = mask[idx];
  unsigned char* rn = rec + (size_t)n * RECB;
  ((unsigned short*)rn)[f] = m ? (unsigned short)0 : f2bf(xv);
  int wave = threadIdx.x >> 6;
  int lane = threadIdx.x & 63;
  unsigned long long bal = __ballot(m != 0);
  if (lane == 0) *(unsigned long long*)(rn + 512 + wave * 8) = bal;
  float cb[KMIX];
#pragma unroll
  for (int k = 0; k < KMIX; ++k) {
    float d = xv - means[k * F + f];
    cb[k] = m ? 0.0f : d * d * ivar[k * F + f];
  }
  __shared__ float red[KMIX][4];
#pragma unroll
  for (int k = 0; k < KMIX; ++k) {
    float c = cb[k];
    for (int off = 32; off > 0; off >>= 1) c += __shfl_down(c, off, 64);
    if (lane == 0) red[k][wave] = c;
  }
  __syncthreads();
  if (threadIdx.x == 0) {
    float lg[KMIX], mx = -1e30f;
#pragma unroll
    for (int k = 0; k < KMIX; ++k) {
      float tot = red[k][0] + red[k][1] + red[k][2] + red[k][3];
      lg[k] = logp[k] - 0.5f * tot;
      mx = fmaxf(mx, lg[k]);
    }
    float den = 0.0f, e[KMIX];
#pragma unroll
    for (int k = 0; k < KMIX; ++k) { e[k] = __expf(lg[k] - mx); den += e[k]; }
    float inv = 1.0f / den;
#pragma unroll
    for (int k = 0; k < KMIX; ++k) gamma[k * Npad + n] = e[k] * inv;
  }
}

// count per (dst, src-group) bucket
__global__ void k_count(const int* __restrict__ edges, int* __restrict__ cnt, int E) {
  int i = blockIdx.x * blockDim.x + threadIdx.x;
  if (i < E) {
    int dst = edges[E + i];
    int g = edges[i] / GS;
    atomicAdd(&cnt[dst * GR + g], 1);
  }
}

// ---- parallel exclusive scan over n = N*GR bucket counts (3 kernels) ----
__global__ __launch_bounds__(1024) void k_scanA(const int* __restrict__ cnt,
                                                int* __restrict__ excl,
                                                int* __restrict__ bsum, int n) {
  __shared__ int s[1024];
  int t = threadIdx.x;
  int i = blockIdx.x * 1024 + t;
  int v = (i < n) ? cnt[i] : 0;
  s[t] = v;
  __syncthreads();
  for (int off = 1; off < 1024; off <<= 1) {
    int u = (t >= off) ? s[t - off] : 0;
    __syncthreads();
    s[t] += u;
    __syncthreads();
  }
  if (i < n) excl[i] = s[t] - v;
  if (t == 1023) bsum[blockIdx.x] = s[1023];
}

__global__ __launch_bounds__(1024) void k_scanB(int* __restrict__ bsum, int nb) {
  __shared__ int s[1024];
  int t = threadIdx.x;
  int v = (t < nb) ? bsum[t] : 0;
  s[t] = v;
  __syncthreads();
  for (int off = 1; off < 1024; off <<= 1) {
    int u = (t >= off) ? s[t - off] : 0;
    __syncthreads();
    s[t] += u;
    __syncthreads();
  }
  if (t < nb) bsum[t] = s[t] - v;   // exclusive block offsets
}

__global__ __launch_bounds__(1024) void k_scanC(int* __restrict__ offs,
                                                int* __restrict__ cur,
                                                const int* __restrict__ bsum,
                                                int n, int E) {
  int i = blockIdx.x * 1024 + threadIdx.x;
  if (i < n) {
    int v = offs[i] + bsum[blockIdx.x];
    offs[i] = v;
    cur[i] = v;
  }
  if (i == 0) offs[n] = E;
}

__global__ void k_fill(const int* __restrict__ edges, int* __restrict__ cur,
                       int* __restrict__ srclist, int E) {
  int i = blockIdx.x * blockDim.x + threadIdx.x;
  if (i < E) {
    int src = edges[i];
    int dst = edges[E + i];
    int g = src / GS;
    int pos = atomicAdd(&cur[dst * GR + g], 1);
    srclist[pos] = src;
  }
}

// One wave per node; 16 nodes/block. srclist is group-sorted per node, so
// concurrently-running waves sweep the 16 x 2 MB record groups in near-lockstep
// -> the hot window stays L2-resident instead of thrashing to L3.
// (round-6 4-wide version: the verified-best; round-7's 8-wide regressed.)
__global__ __launch_bounds__(1024) void k_gather(
    const unsigned char* __restrict__ rec,
    const int* __restrict__ offs, const int* __restrict__ srclist,
    unsigned short* __restrict__ xs_pack, unsigned short* __restrict__ sm_pack,
    float* __restrict__ degp1) {
  __shared__ float xs_l[16][257];
  __shared__ float sm_l[16][257];
  int tile = blockIdx.x;
  int wave = threadIdx.x >> 6, lane = threadIdx.x & 63;
  int fb = lane * 4;
  int n = tile * 16 + wave;
  const unsigned char* rn = rec + (size_t)n * RECB;
  ushort4 xv = *(const ushort4*)(rn + lane * 8);
  unsigned int mw = *(const unsigned int*)(rn + 512 + ((lane >> 3) << 2));
  unsigned int nib = (mw >> ((lane & 7) * 4)) & 0xFu;
  unsigned int macc = (nib | (nib << 7) | (nib << 14) | (nib << 21)) & 0x01010101u;
  float a0 = bf2f(xv.x), a1 = bf2f(xv.y), a2 = bf2f(xv.z), a3 = bf2f(xv.w);
  int s0 = offs[n * GR], s1 = offs[n * GR + GR];   // contiguous across groups
  int i = s0;
  int nsa = 0, nsb = 0, nsc = 0, nsd = 0;
  if (i + 4 <= s1) {
    nsa = srclist[i]; nsb = srclist[i + 1]; nsc = srclist[i + 2]; nsd = srclist[i + 3];
  }
  while (i + 4 <= s1) {
    int sa = nsa, sb = nsb, sc = nsc, sd = nsd;
    const unsigned char* ra = rec + (size_t)sa * RECB;
    const unsigned char* rb = rec + (size_t)sb * RECB;
    const unsigned char* rc = rec + (size_t)sc * RECB;
    const unsigned char* rd = rec + (size_t)sd * RECB;
    ushort4 va = *(const ushort4*)(ra + lane * 8);
    ushort4 vb = *(const ushort4*)(rb + lane * 8);
    ushort4 vc = *(const ushort4*)(rc + lane * 8);
    ushort4 vd = *(const ushort4*)(rd + lane * 8);
    unsigned int wa = *(const unsigned int*)(ra + 512 + ((lane >> 3) << 2));
    unsigned int wb = *(const unsigned int*)(rb + 512 + ((lane >> 3) << 2));
    unsigned int wc = *(const unsigned int*)(rc + 512 + ((lane >> 3) << 2));
    unsigned int wd = *(const unsigned int*)(rd + 512 + ((lane >> 3) << 2));
    i += 4;
    if (i + 4 <= s1) {   // prefetch next indices before waiting on the gathers
      nsa = srclist[i]; nsb = srclist[i + 1]; nsc = srclist[i + 2]; nsd = srclist[i + 3];
    }
    a0 += bf2f(va.x) + bf2f(vb.x) + bf2f(vc.x) + bf2f(vd.x);
    a1 += bf2f(va.y) + bf2f(vb.y) + bf2f(vc.y) + bf2f(vd.y);
    a2 += bf2f(va.z) + bf2f(vb.z) + bf2f(vc.z) + bf2f(vd.z);
    a3 += bf2f(va.w) + bf2f(vb.w) + bf2f(vc.w) + bf2f(vd.w);
    unsigned int na = (wa >> ((lane & 7) * 4)) & 0xFu;
    unsigned int nb = (wb >> ((lane & 7) * 4)) & 0xFu;
    unsigned int nc = (wc >> ((lane & 7) * 4)) & 0xFu;
    unsigned int nd = (wd >> ((lane & 7) * 4)) & 0xFu;
    macc += (na | (na << 7) | (na << 14) | (na << 21)) & 0x01010101u;
    macc += (nb | (nb << 7) | (nb << 14) | (nb << 21)) & 0x01010101u;
    macc += (nc | (nc << 7) | (nc << 14) | (nc << 21)) & 0x01010101u;
    macc += (nd | (nd << 7) | (nd << 14) | (nd << 21)) & 0x01010101u;
  }
  for (; i < s1; ++i) {
    int s = srclist[i];
    const unsigned char* rs = rec + (size_t)s * RECB;
    ushort4 sv = *(const ushort4*)(rs + lane * 8);
    unsigned int ws = *(const unsigned int*)(rs + 512 + ((lane >> 3) << 2));
    a0 += bf2f(sv.x); a1 += bf2f(sv.y); a2 += bf2f(sv.z); a3 += bf2f(sv.w);
    unsigned int ns = (ws >> ((lane & 7) * 4)) & 0xFu;
    macc += (ns | (ns << 7) | (ns << 14) | (ns << 21)) & 0x01010101u;
  }
  xs_l[wave][fb] = a0; xs_l[wave][fb + 1] = a1; xs_l[wave][fb + 2] = a2; xs_l[wave][fb + 3] = a3;
  sm_l[wave][fb] = (float)(macc & 0xFFu);
  sm_l[wave][fb + 1] = (float)((macc >> 8) & 0xFFu);
  sm_l[wave][fb + 2] = (float)((macc >> 16) & 0xFFu);
  sm_l[wave][fb + 3] = (float)(macc >> 24);
  if (lane == 0) degp1[n] = (float)(s1 - s0 + 1);
  __syncthreads();
  if (threadIdx.x < 512) {
    int slot = threadIdx.x;
    int kt = slot >> 6, l = slot & 63;
    int r = l & 15, q = l >> 4;
    int fbase = kt * 32 + q * 8;
    bf16x8 vx, vs;
#pragma unroll
    for (int j = 0; j < 8; ++j) {
      vx[j] = (short)f2bf(xs_l[r][fbase + j]);
      vs[j] = (short)f2bf(sm_l[r][fbase + j]);
    }
    long long po = ((long long)tile * 8 + kt) * 64 + l;
    ((bf16x8*)xs_pack)[po] = vx;
    ((bf16x8*)sm_pack)[po] = vs;
  }
}

// Pack 11 B-matrices in MFMA B-fragment order (m=0: W; 1..5: means_k*W; 6..10: var_k*W^2)
__global__ __launch_bounds__(64) void k_bpack(
    const float* __restrict__ weight, const float* __restrict__ means,
    const float* __restrict__ logvars, unsigned short* __restrict__ bpack) {
  int bid = blockIdx.x;
  int kt = bid & 7, ot = (bid >> 3) & 15, m = bid >> 7;
  int l = threadIdx.x;
  int r = l & 15, q = l >> 4;
  int o = ot * 16 + r;
  bf16x8 v;
#pragma unroll
  for (int j = 0; j < 8; ++j) {
    int f = kt * 32 + q * 8 + j;
    float wv = weight[f * F + o];
    float val;
    if (m == 0) val = wv;
    else if (m <= 5) val = means[(m - 1) * F + f] * wv;
    else val = __expf(logvars[(m - 6) * F + f]) * wv * wv;
    v[j] = (short)f2bf(val);
  }
  ((bf16x8*)bpack)[((long long)(m * 16 + ot) * 8 + kt) * 64 + l] = v;
}

// Fused GEMM + ex_relu + gamma-weighted k-reduction.
// Round-12 = round-6 verified base (199 us: 2x2 waves, (256,3), bias fold,
// runtime k-loop) with ONE change: #pragma unroll 2 on the k-loop.
// Round-7's full 5x unroll spilled (FETCH 49->405 MB): live state of 5
// iterations > the 170-reg cap. 2x keeps one extra gm/ax/ac set (~+35 regs,
// ~120-145 total < 170). Mechanism: k+1's loads+MFMAs (matrix pipe) overlap
// k's ex_relu epilogue (VALU pipe) — measured MfmaUtil ~= VALUBusy ~= 14.5%
// means each pipe idles while the other runs; the pipes are independent.
// GUARD: FETCH > 100 MB here = unroll-2 also spilled -> round-6 plain is floor.
// DO NOT raise waves/SIMD via launch_bounds: (256,4) spilled twice (r1, r5).
__global__ __launch_bounds__(256, 3) void k_gemm(
    const unsigned short* __restrict__ xs_pack, const unsigned short* __restrict__ sm_pack,
    const unsigned short* __restrict__ bpack, const float* __restrict__ degp1,
    const float* __restrict__ gamma, const float* __restrict__ bias,
    float* __restrict__ out, int N, int Npad, int RB) {
  int L = blockIdx.x;
  int rb = (L >> 5) * 8 + (L & 7);     // 64-row slice; L%8 -> XCD (4 bo of one rb share XCD)
  int bo = (L >> 3) & 3;               // 64-col block
  if (rb >= RB) return;
  __shared__ unsigned char sp_lds[32768];
  int tid = threadIdx.x;
  int wave = tid >> 6, lane = tid & 63;
  int rw = wave >> 1, cw = wave & 1;   // row-wave, col-wave
  int q = lane >> 4, r16 = lane & 15;
  int rt0 = rb * 4 + rw * 2;           // first 16-row tile of this wave
  int ct0 = bo * 4 + cw * 2;           // first 16-col tile of this wave
  const bf16x8* XP = (const bf16x8*)xs_pack;
  const bf16x8* BP = (const bf16x8*)bpack;

  // cooperative stage: SP slice for rows [rb*64, +64) -> LDS (32 KB)
  {
    const uint4* src = (const uint4*)((const unsigned char*)sm_pack + (size_t)rb * 32768) + tid;
    uint4* dst = (uint4*)(void*)sp_lds + tid;
#pragma unroll
    for (int it = 0; it < 8; ++it) dst[it * 256] = src[it * 256];
  }

  // C1 = xs @ W (shared across all k) — overlaps LDS staging
  f32x4 C1[2][2];
#pragma unroll
  for (int rt = 0; rt < 2; ++rt)
#pragma unroll
    for (int cc = 0; cc < 2; ++cc) C1[rt][cc] = (f32x4){0.f, 0.f, 0.f, 0.f};
#pragma unroll
  for (int kt = 0; kt < 8; ++kt) {
    bf16x8 a0 = XP[((size_t)rt0 * 8 + kt) * 64 + lane];
    bf16x8 a1 = XP[((size_t)(rt0 + 1) * 8 + kt) * 64 + lane];
#pragma unroll
    for (int cc = 0; cc < 2; ++cc) {
      bf16x8 b = BP[((size_t)(ct0 + cc) * 8 + kt) * 64 + lane];
      C1[0][cc] = MFMA(a0, b, C1[0][cc]);
      C1[1][cc] = MFMA(a1, b, C1[1][cc]);
    }
  }

  int row0 = rb * 64 + rw * 32 + q * 4;
  // fold deg*bias into C1: mu_k = C1' + sum_kt sp.bw_k  (dp/bs dead after this)
  {
    float dp[2][4];
#pragma unroll
    for (int rt = 0; rt < 2; ++rt)
#pragma unroll
      for (int rr = 0; rr < 4; ++rr) dp[rt][rr] = degp1[row0 + rt * 16 + rr];
    float bs[2];
#pragma unroll
    for (int cc = 0; cc < 2; ++cc) bs[cc] = bias[bo * 64 + cw * 32 + cc * 16 + r16];
#pragma unroll
    for (int rt = 0; rt < 2; ++rt)
#pragma unroll
      for (int cc = 0; cc < 2; ++cc)
#pragma unroll
        for (int rr = 0; rr < 4; ++rr) C1[rt][cc][rr] += dp[rt][rr] * bs[cc];
  }

  f32x4 outa[2][2];
#pragma unroll
  for (int rt = 0; rt < 2; ++rt)
#pragma unroll
    for (int cc = 0; cc < 2; ++cc) outa[rt][cc] = (f32x4){0.f, 0.f, 0.f, 0.f};

  __syncthreads();
  const unsigned char* myl = sp_lds + rw * 16384;   // this row-wave's 32-row SP slice

#pragma unroll 2
  for (int k = 0; k < KMIX; ++k) {
    float gm[2][4];
#pragma unroll
    for (int rt = 0; rt < 2; ++rt)
#pragma unroll
      for (int rr = 0; rr < 4; ++rr) gm[rt][rr] = gamma[k * Npad + row0 + rt * 16 + rr];
    f32x4 ax[2][2], ac[2][2];
#pragma unroll
    for (int rt = 0; rt < 2; ++rt)
#pragma unroll
      for (int cc = 0; cc < 2; ++cc) {
        ax[rt][cc] = C1[rt][cc];
        ac[rt][cc] = (f32x4){0.f, 0.f, 0.f, 0.f};
      }
#pragma unroll
    for (int kt = 0; kt < 8; ++kt) {
      bf16x8 sp0 = *(const bf16x8*)(myl + kt * 1024 + lane * 16);
      bf16x8 sp1 = *(const bf16x8*)(myl + 8192 + kt * 1024 + lane * 16);
#pragma unroll
      for (int cc = 0; cc < 2; ++cc) {
        int c = ct0 + cc;
        bf16x8 bw = BP[(((size_t)(1 + k) * 16 + c) * 8 + kt) * 64 + lane];
        bf16x8 bv = BP[(((size_t)(6 + k) * 16 + c) * 8 + kt) * 64 + lane];
        ax[0][cc] = MFMA(sp0, bw, ax[0][cc]);
        ax[1][cc] = MFMA(sp1, bw, ax[1][cc]);
        ac[0][cc] = MFMA(sp0, bv, ac[0][cc]);
        ac[1][cc] = MFMA(sp1, bv, ac[1][cc]);
      }
    }
#pragma unroll
    for (int rt = 0; rt < 2; ++rt)
#pragma unroll
      for (int cc = 0; cc < 2; ++cc)
#pragma unroll
        for (int rr = 0; rr < 4; ++rr) {
          float e = ex_relu_fast(ax[rt][cc][rr], ac[rt][cc][rr]);
          outa[rt][cc][rr] += gm[rt][rr] * e;
        }
  }

#pragma unroll
  for (int rt = 0; rt < 2; ++rt)
#pragma unroll
    for (int cc = 0; cc < 2; ++cc) {
      int col = bo * 64 + cw * 32 + cc * 16 + r16;
#pragma unroll
      for (int rr = 0; rr < 4; ++rr) {
        int row = row0 + rt * 16 + rr;
        if (row < N) out[(long long)row * F + col] = outa[rt][cc][rr];
      }
    }
}

extern "C" void kernel_launch(void* const* d_in, const int* in_sizes, int n_in,
                              void* d_out, int out_size, void* d_ws, size_t ws_size,
                              hipStream_t stream) {
  const float* x = (const float*)d_in[0];
  const int* edges = (const int*)d_in[1];
  const int* mask = (const int*)d_in[2];
  const float* logp = (const float*)d_in[3];
  const float* means = (const float*)d_in[4];
  const float* logvars = (const float*)d_in[5];
  const float* weight = (const float*)d_in[6];
  const float* bias = (const float*)d_in[7];
  float* out = (float*)d_out;

  int N = in_sizes[0] / F;              // 50000
  int E = in_sizes[1] / 2;              // 1600000
  int Npad = ((N + 127) / 128) * 128;   // 50048
  int RB = Npad / 64;                   // 782 row slices of 64
  int NB = N * GR;                      // bucket count
  int SB = (NB + 1023) / 1024;          // scan blocks (782 <= 1024)

  char* w = (char*)d_ws;
  auto alloc = [&](size_t bytes) {
    char* p = w;
    w += (bytes + 255) & ~(size_t)255;
    return p;
  };
  unsigned char* rec = (unsigned char*)alloc((size_t)N * RECB);
  unsigned short* xsp = (unsigned short*)alloc((size_t)Npad * F * 2);
  unsigned short* smp = (unsigned short*)alloc((size_t)Npad * F * 2);
  unsigned short* bpk = (unsigned short*)alloc((size_t)11 * F * F * 2);
  int* cnt = (int*)alloc((size_t)NB * 4);
  int* offs = (int*)alloc((size_t)(NB + 1) * 4);
  int* cur = (int*)alloc((size_t)NB * 4);
  int* bsum = (int*)alloc((size_t)1024 * 4);
  int* srclist = (int*)alloc((size_t)E * 4);
  float* degp1 = (float*)alloc((size_t)Npad * 4);
  float* gamma = (float*)alloc((size_t)KMIX * Npad * 4);
  float* ivar = (float*)alloc((size_t)KMIX * F * 4);

  kzero<<<782, 256, 0, stream>>>((unsigned int*)cnt, NB);
  k_tab<<<(KMIX * F + 255) / 256, 256, 0, stream>>>(logvars, ivar);
  k_prep<<<N, 256, 0, stream>>>(x, mask, logp, means, ivar, rec, gamma, Npad);
  k_count<<<(E + 255) / 256, 256, 0, stream>>>(edges, cnt, E);
  k_scanA<<<SB, 1024, 0, stream>>>(cnt, offs, bsum, NB);
  k_scanB<<<1, 1024, 0, stream>>>(bsum, SB);
  k_scanC<<<SB, 1024, 0, stream>>>(offs, cur, bsum, NB, E);
  k_fill<<<(E + 255) / 256, 256, 0, stream>>>(edges, cur, srclist, E);
  k_gather<<<N / 16, 1024, 0, stream>>>(rec, offs, srclist, xsp, smp, degp1);
  k_bpack<<<11 * 16 * 8, 64, 0, stream>>>(weight, means, logvars, bpk);
  int NGG = (RB + 7) / 8;
  k_gemm<<<NGG * 32, 256, 0, stream>>>(xsp, smp, bpk, degp1, gamma, bias, out, N, Npad, RB);
}

// Round 10
// 740.410 us; speedup vs baseline: 1.5348x; 1.5348x over previous
//
#include <hip/hip_runtime.h>
#include <math.h>

#define F 256
#define KMIX 5
#define RECB 640     // node record: 512 B bf16 xm + 32 B mask bits + 96 B pad
#define GR 16        // source-node groups (L2 locality phases)
#define GS 3136      // group size: 16*3136 = 50176 >= N; 3136*640 B = 2.0 MB per group

typedef __attribute__((ext_vector_type(8))) short bf16x8;
typedef __attribute__((ext_vector_type(4))) float f32x4;

__device__ __forceinline__ float bf2f(unsigned short u) {
  union { unsigned int i; float f; } v; v.i = ((unsigned int)u) << 16; return v.f;
}
__device__ __forceinline__ unsigned short f2bf(float f) {
  union { float f; unsigned int i; } v; v.f = f;
  unsigned int u = v.i;
  unsigned int r = (u + 0x7fffu + ((u >> 16) & 1u)) >> 16;
  return (unsigned short)r;
}

__device__ __forceinline__ f32x4 MFMA(bf16x8 a, bf16x8 b, f32x4 c) {
  return __builtin_amdgcn_mfma_f32_16x16x32_bf16(a, b, c, 0, 0, 0);
}

// Fast E[relu(N(mu,sigma))]: 0.5*mu + 0.5*(mu^2+c1*sig)*rsqrt(mu^2+2*c1*sig), c1=4/pi.
// Exact at w=0 and asymptotes; max abs err ~0.025*sqrt(sig). sigma==0 -> max(mu,0).
__device__ __forceinline__ float ex_relu_fast(float mu, float sig) {
  const float c1 = 1.2732395447f;
  const float c2 = 2.5464790895f;
  float t = mu * mu;
  float u = t + c1 * sig;
  float v = t + c2 * sig + 1e-20f;
  float r = __builtin_amdgcn_rsqf(v);
  return 0.5f * mu + 0.5f * u * r;
}

__global__ void kzero(unsigned int* p, long long n) {
  long long i = (long long)blockIdx.x * blockDim.x + threadIdx.x;
  long long stride = (long long)gridDim.x * blockDim.x;
  for (; i < n; i += stride) p[i] = 0u;
}

// ivar[k][f] = exp(-logvars[k][f])
__global__ __launch_bounds__(256) void k_tab(const float* __restrict__ logvars,
                                             float* __restrict__ ivar) {
  int i = blockIdx.x * 256 + threadIdx.x;
  if (i < KMIX * F) ivar[i] = __expf(-logvars[i]);
}

// Per-node: record = [bf16 xm | bit mask], gamma = softmax_k(logp - 0.5*sum diff2)
// (reference's -0.5*F*log(2pi) and -0.5*sum(logvars) are k-independent -> cancel)
__global__ __launch_bounds__(256) void k_prep(
    const float* __restrict__ x, const int* __restrict__ mask,
    const float* __restrict__ logp, const float* __restrict__ means,
    const float* __restrict__ ivar,
    unsigned char* __restrict__ rec, float* __restrict__ gamma, int Npad) {
  int n = blockIdx.x;
  int f = threadIdx.x;
  int idx = n * F + f;
  float xv = x[idx];
  int m = mask[idx];
  unsigned char* rn = rec + (size_t)n * RECB;
  ((unsigned short*)rn)[f] = m ? (unsigned short)0 : f2bf(xv);
  int wave = threadIdx.x >> 6;
  int lane = threadIdx.x & 63;
  unsigned long long bal = __ballot(m != 0);
  if (lane == 0) *(unsigned long long*)(rn + 512 + wave * 8) = bal;
  float cb[KMIX];
#pragma unroll
  for (int k = 0; k < KMIX; ++k) {
    float d = xv - means[k * F + f];
    cb[k] = m ? 0.0f : d * d * ivar[k * F + f];
  }
  __shared__ float red[KMIX][4];
#pragma unroll
  for (int k = 0; k < KMIX; ++k) {
    float c = cb[k];
    for (int off = 32; off > 0; off >>= 1) c += __shfl_down(c, off, 64);
    if (lane == 0) red[k][wave] = c;
  }
  __syncthreads();
  if (threadIdx.x == 0) {
    float lg[KMIX], mx = -1e30f;
#pragma unroll
    for (int k = 0; k < KMIX; ++k) {
      float tot = red[k][0] + red[k][1] + red[k][2] + red[k][3];
      lg[k] = logp[k] - 0.5f * tot;
      mx = fmaxf(mx, lg[k]);
    }
    float den = 0.0f, e[KMIX];
#pragma unroll
    for (int k = 0; k < KMIX; ++k) { e[k] = __expf(lg[k] - mx); den += e[k]; }
    float inv = 1.0f / den;
#pragma unroll
    for (int k = 0; k < KMIX; ++k) gamma[k * Npad + n] = e[k] * inv;
  }
}

// count per (dst, src-group) bucket
__global__ void k_count(const int* __restrict__ edges, int* __restrict__ cnt, int E) {
  int i = blockIdx.x * blockDim.x + threadIdx.x;
  if (i < E) {
    int dst = edges[E + i];
    int g = edges[i] / GS;
    atomicAdd(&cnt[dst * GR + g], 1);
  }
}

// ---- parallel exclusive scan over n = N*GR bucket counts (3 kernels) ----
__global__ __launch_bounds__(1024) void k_scanA(const int* __restrict__ cnt,
                                                int* __restrict__ excl,
                                                int* __restrict__ bsum, int n) {
  __shared__ int s[1024];
  int t = threadIdx.x;
  int i = blockIdx.x * 1024 + t;
  int v = (i < n) ? cnt[i] : 0;
  s[t] = v;
  __syncthreads();
  for (int off = 1; off < 1024; off <<= 1) {
    int u = (t >= off) ? s[t - off] : 0;
    __syncthreads();
    s[t] += u;
    __syncthreads();
  }
  if (i < n) excl[i] = s[t] - v;
  if (t == 1023) bsum[blockIdx.x] = s[1023];
}

__global__ __launch_bounds__(1024) void k_scanB(int* __restrict__ bsum, int nb) {
  __shared__ int s[1024];
  int t = threadIdx.x;
  int v = (t < nb) ? bsum[t] : 0;
  s[t] = v;
  __syncthreads();
  for (int off = 1; off < 1024; off <<= 1) {
    int u = (t >= off) ? s[t - off] : 0;
    __syncthreads();
    s[t] += u;
    __syncthreads();
  }
  if (t < nb) bsum[t] = s[t] - v;   // exclusive block offsets
}

__global__ __launch_bounds__(1024) void k_scanC(int* __restrict__ offs,
                                                int* __restrict__ cur,
                                                const int* __restrict__ bsum,
                                                int n, int E) {
  int i = blockIdx.x * 1024 + threadIdx.x;
  if (i < n) {
    int v = offs[i] + bsum[blockIdx.x];
    offs[i] = v;
    cur[i] = v;
  }
  if (i == 0) offs[n] = E;
}

__global__ void k_fill(const int* __restrict__ edges, int* __restrict__ cur,
                       int* __restrict__ srclist, int E) {
  int i = blockIdx.x * blockDim.x + threadIdx.x;
  if (i < E) {
    int src = edges[i];
    int dst = edges[E + i];
    int g = src / GS;
    int pos = atomicAdd(&cur[dst * GR + g], 1);
    srclist[pos] = src;
  }
}

// One wave per node; 16 nodes/block. srclist is group-sorted per node, so
// concurrently-running waves sweep the 16 x 2 MB record groups in near-lockstep
// -> the hot window stays L2-resident instead of thrashing to L3.
// (round-6 4-wide version: the verified-best; round-7's 8-wide regressed.)
__global__ __launch_bounds__(1024) void k_gather(
    const unsigned char* __restrict__ rec,
    const int* __restrict__ offs, const int* __restrict__ srclist,
    unsigned short* __restrict__ xs_pack, unsigned short* __restrict__ sm_pack,
    float* __restrict__ degp1) {
  __shared__ float xs_l[16][257];
  __shared__ float sm_l[16][257];
  int tile = blockIdx.x;
  int wave = threadIdx.x >> 6, lane = threadIdx.x & 63;
  int fb = lane * 4;
  int n = tile * 16 + wave;
  const unsigned char* rn = rec + (size_t)n * RECB;
  ushort4 xv = *(const ushort4*)(rn + lane * 8);
  unsigned int mw = *(const unsigned int*)(rn + 512 + ((lane >> 3) << 2));
  unsigned int nib = (mw >> ((lane & 7) * 4)) & 0xFu;
  unsigned int macc = (nib | (nib << 7) | (nib << 14) | (nib << 21)) & 0x01010101u;
  float a0 = bf2f(xv.x), a1 = bf2f(xv.y), a2 = bf2f(xv.z), a3 = bf2f(xv.w);
  int s0 = offs[n * GR], s1 = offs[n * GR + GR];   // contiguous across groups
  int i = s0;
  int nsa = 0, nsb = 0, nsc = 0, nsd = 0;
  if (i + 4 <= s1) {
    nsa = srclist[i]; nsb = srclist[i + 1]; nsc = srclist[i + 2]; nsd = srclist[i + 3];
  }
  while (i + 4 <= s1) {
    int sa = nsa, sb = nsb, sc = nsc, sd = nsd;
    const unsigned char* ra = rec + (size_t)sa * RECB;
    const unsigned char* rb = rec + (size_t)sb * RECB;
    const unsigned char* rc = rec + (size_t)sc * RECB;
    const unsigned char* rd = rec + (size_t)sd * RECB;
    ushort4 va = *(const ushort4*)(ra + lane * 8);
    ushort4 vb = *(const ushort4*)(rb + lane * 8);
    ushort4 vc = *(const ushort4*)(rc + lane * 8);
    ushort4 vd = *(const ushort4*)(rd + lane * 8);
    unsigned int wa = *(const unsigned int*)(ra + 512 + ((lane >> 3) << 2));
    unsigned int wb = *(const unsigned int*)(rb + 512 + ((lane >> 3) << 2));
    unsigned int wc = *(const unsigned int*)(rc + 512 + ((lane >> 3) << 2));
    unsigned int wd = *(const unsigned int*)(rd + 512 + ((lane >> 3) << 2));
    i += 4;
    if (i + 4 <= s1) {   // prefetch next indices before waiting on the gathers
      nsa = srclist[i]; nsb = srclist[i + 1]; nsc = srclist[i + 2]; nsd = srclist[i + 3];
    }
    a0 += bf2f(va.x) + bf2f(vb.x) + bf2f(vc.x) + bf2f(vd.x);
    a1 += bf2f(va.y) + bf2f(vb.y) + bf2f(vc.y) + bf2f(vd.y);
    a2 += bf2f(va.z) + bf2f(vb.z) + bf2f(vc.z) + bf2f(vd.z);
    a3 += bf2f(va.w) + bf2f(vb.w) + bf2f(vc.w) + bf2f(vd.w);
    unsigned int na = (wa >> ((lane & 7) * 4)) & 0xFu;
    unsigned int nb = (wb >> ((lane & 7) * 4)) & 0xFu;
    unsigned int nc = (wc >> ((lane & 7) * 4)) & 0xFu;
    unsigned int nd = (wd >> ((lane & 7) * 4)) & 0xFu;
    macc += (na | (na << 7) | (na << 14) | (na << 21)) & 0x01010101u;
    macc += (nb | (nb << 7) | (nb << 14) | (nb << 21)) & 0x01010101u;
    macc += (nc | (nc << 7) | (nc << 14) | (nc << 21)) & 0x01010101u;
    macc += (nd | (nd << 7) | (nd << 14) | (nd << 21)) & 0x01010101u;
  }
  for (; i < s1; ++i) {
    int s = srclist[i];
    const unsigned char* rs = rec + (size_t)s * RECB;
    ushort4 sv = *(const ushort4*)(rs + lane * 8);
    unsigned int ws = *(const unsigned int*)(rs + 512 + ((lane >> 3) << 2));
    a0 += bf2f(sv.x); a1 += bf2f(sv.y); a2 += bf2f(sv.z); a3 += bf2f(sv.w);
    unsigned int ns = (ws >> ((lane & 7) * 4)) & 0xFu;
    macc += (ns | (ns << 7) | (ns << 14) | (ns << 21)) & 0x01010101u;
  }
  xs_l[wave][fb] = a0; xs_l[wave][fb + 1] = a1; xs_l[wave][fb + 2] = a2; xs_l[wave][fb + 3] = a3;
  sm_l[wave][fb] = (float)(macc & 0xFFu);
  sm_l[wave][fb + 1] = (float)((macc >> 8) & 0xFFu);
  sm_l[wave][fb + 2] = (float)((macc >> 16) & 0xFFu);
  sm_l[wave][fb + 3] = (float)(macc >> 24);
  if (lane == 0) degp1[n] = (float)(s1 - s0 + 1);
  __syncthreads();
  if (threadIdx.x < 512) {
    int slot = threadIdx.x;
    int kt = slot >> 6, l = slot & 63;
    int r = l & 15, q = l >> 4;
    int fbase = kt * 32 + q * 8;
    bf16x8 vx, vs;
#pragma unroll
    for (int j = 0; j < 8; ++j) {
      vx[j] = (short)f2bf(xs_l[r][fbase + j]);
      vs[j] = (short)f2bf(sm_l[r][fbase + j]);
    }
    long long po = ((long long)tile * 8 + kt) * 64 + l;
    ((bf16x8*)xs_pack)[po] = vx;
    ((bf16x8*)sm_pack)[po] = vs;
  }
}

// Pack B-matrices in MFMA B-fragment order.
// Layout (bf16x8 units): [0, 8192): W as [ot][kt][lane].
// [8192, ...): paired k-matrices: (((k*16+ot)*8+kt)*64+lane)*2 + s,
//   s=0: means_k*W fragment, s=1: var_k*W^2 fragment. Each lane's (bw,bv)
//   pair is 32 B contiguous -> one address base, bv always L1-hits behind bw.
__global__ __launch_bounds__(64) void k_bpack(
    const float* __restrict__ weight, const float* __restrict__ means,
    const float* __restrict__ logvars, unsigned short* __restrict__ bpack) {
  int bid = blockIdx.x;
  int kt = bid & 7, ot = (bid >> 3) & 15, m = bid >> 7;
  int l = threadIdx.x;
  int r = l & 15, q = l >> 4;
  int o = ot * 16 + r;
  bf16x8 v;
#pragma unroll
  for (int j = 0; j < 8; ++j) {
    int f = kt * 32 + q * 8 + j;
    float wv = weight[f * F + o];
    float val;
    if (m == 0) val = wv;
    else if (m <= 5) val = means[(m - 1) * F + f] * wv;
    else val = __expf(logvars[(m - 6) * F + f]) * wv * wv;
    v[j] = (short)f2bf(val);
  }
  size_t idx;
  if (m == 0) {
    idx = ((size_t)ot * 8 + kt) * 64 + l;
  } else {
    int s = (m <= 5) ? 0 : 1;
    int k = (m <= 5) ? (m - 1) : (m - 6);
    idx = 8192 + ((((size_t)k * 16 + ot) * 8 + kt) * 64 + l) * 2 + s;
  }
  ((bf16x8*)bpack)[idx] = v;
}

// Fused GEMM + ex_relu + gamma-weighted k-reduction.
// Round-13 = round-6 verified base (199 us: 2x2 waves, (256,3), bias fold,
// RUNTIME k-loop — every unroll variant spilled: r7 full 5x, r8 even 2x;
// the body sits ~148/170 regs, +1 iteration of live state is over the cliff)
// with ONE single-variable change: paired (bw,bv) BP layout. Mechanism: the
// per-k stall is ~16 sequential load-use events at L2/L3 latency (compiler
// can only keep ~5 loads in flight — no spare regs). Pairing makes bv a
// guaranteed L1 hit 16 B behind bw: long-latency events per k halve (16->8),
// and the two 655-KB-apart address bases merge into one base+imm16 (frees
// address SGPRs/VGPRs). Never fairly tested: r5/r7 measurements were
// confounded by simultaneous spills.
// GUARD: FETCH > 100 MB = spill -> revert to round-6 exact.
__global__ __launch_bounds__(256, 3) void k_gemm(
    const unsigned short* __restrict__ xs_pack, const unsigned short* __restrict__ sm_pack,
    const unsigned short* __restrict__ bpack, const float* __restrict__ degp1,
    const float* __restrict__ gamma, const float* __restrict__ bias,
    float* __restrict__ out, int N, int Npad, int RB) {
  int L = blockIdx.x;
  int rb = (L >> 5) * 8 + (L & 7);     // 64-row slice; L%8 -> XCD (4 bo of one rb share XCD)
  int bo = (L >> 3) & 3;               // 64-col block
  if (rb >= RB) return;
  __shared__ unsigned char sp_lds[32768];
  int tid = threadIdx.x;
  int wave = tid >> 6, lane = tid & 63;
  int rw = wave >> 1, cw = wave & 1;   // row-wave, col-wave
  int q = lane >> 4, r16 = lane & 15;
  int rt0 = rb * 4 + rw * 2;           // first 16-row tile of this wave
  int ct0 = bo * 4 + cw * 2;           // first 16-col tile of this wave
  const bf16x8* XP = (const bf16x8*)xs_pack;
  const bf16x8* BP = (const bf16x8*)bpack;
  const bf16x8* BPp = BP + 8192;       // paired (w,v) region

  // cooperative stage: SP slice for rows [rb*64, +64) -> LDS (32 KB)
  {
    const uint4* src = (const uint4*)((const unsigned char*)sm_pack + (size_t)rb * 32768) + tid;
    uint4* dst = (uint4*)(void*)sp_lds + tid;
#pragma unroll
    for (int it = 0; it < 8; ++it) dst[it * 256] = src[it * 256];
  }

  // C1 = xs @ W (shared across all k) — overlaps LDS staging
  f32x4 C1[2][2];
#pragma unroll
  for (int rt = 0; rt < 2; ++rt)
#pragma unroll
    for (int cc = 0; cc < 2; ++cc) C1[rt][cc] = (f32x4){0.f, 0.f, 0.f, 0.f};
#pragma unroll
  for (int kt = 0; kt < 8; ++kt) {
    bf16x8 a0 = XP[((size_t)rt0 * 8 + kt) * 64 + lane];
    bf16x8 a1 = XP[((size_t)(rt0 + 1) * 8 + kt) * 64 + lane];
#pragma unroll
    for (int cc = 0; cc < 2; ++cc) {
      bf16x8 b = BP[((size_t)(ct0 + cc) * 8 + kt) * 64 + lane];
      C1[0][cc] = MFMA(a0, b, C1[0][cc]);
      C1[1][cc] = MFMA(a1, b, C1[1][cc]);
    }
  }

  int row0 = rb * 64 + rw * 32 + q * 4;
  // fold deg*bias into C1: mu_k = C1' + sum_kt sp.bw_k  (dp/bs dead after this)
  {
    float dp[2][4];
#pragma unroll
    for (int rt = 0; rt < 2; ++rt)
#pragma unroll
      for (int rr = 0; rr < 4; ++rr) dp[rt][rr] = degp1[row0 + rt * 16 + rr];
    float bs[2];
#pragma unroll
    for (int cc = 0; cc < 2; ++cc) bs[cc] = bias[bo * 64 + cw * 32 + cc * 16 + r16];
#pragma unroll
    for (int rt = 0; rt < 2; ++rt)
#pragma unroll
      for (int cc = 0; cc < 2; ++cc)
#pragma unroll
        for (int rr = 0; rr < 4; ++rr) C1[rt][cc][rr] += dp[rt][rr] * bs[cc];
  }

  f32x4 outa[2][2];
#pragma unroll
  for (int rt = 0; rt < 2; ++rt)
#pragma unroll
    for (int cc = 0; cc < 2; ++cc) outa[rt][cc] = (f32x4){0.f, 0.f, 0.f, 0.f};

  __syncthreads();
  const unsigned char* myl = sp_lds + rw * 16384;   // this row-wave's 32-row SP slice

  for (int k = 0; k < KMIX; ++k) {
    float gm[2][4];
#pragma unroll
    for (int rt = 0; rt < 2; ++rt)
#pragma unroll
      for (int rr = 0; rr < 4; ++rr) gm[rt][rr] = gamma[k * Npad + row0 + rt * 16 + rr];
    f32x4 ax[2][2], ac[2][2];
#pragma unroll
    for (int rt = 0; rt < 2; ++rt)
#pragma unroll
      for (int cc = 0; cc < 2; ++cc) {
        ax[rt][cc] = C1[rt][cc];
        ac[rt][cc] = (f32x4){0.f, 0.f, 0.f, 0.f};
      }
#pragma unroll
    for (int kt = 0; kt < 8; ++kt) {
      bf16x8 sp0 = *(const bf16x8*)(myl + kt * 1024 + lane * 16);
      bf16x8 sp1 = *(const bf16x8*)(myl + 8192 + kt * 1024 + lane * 16);
#pragma unroll
      for (int cc = 0; cc < 2; ++cc) {
        int c = ct0 + cc;
        const bf16x8* pp = &BPp[((((size_t)k * 16 + c) * 8 + kt) * 64 + lane) * 2];
        bf16x8 bw = pp[0];
        bf16x8 bv = pp[1];
        ax[0][cc] = MFMA(sp0, bw, ax[0][cc]);
        ax[1][cc] = MFMA(sp1, bw, ax[1][cc]);
        ac[0][cc] = MFMA(sp0, bv, ac[0][cc]);
        ac[1][cc] = MFMA(sp1, bv, ac[1][cc]);
      }
    }
#pragma unroll
    for (int rt = 0; rt < 2; ++rt)
#pragma unroll
      for (int cc = 0; cc < 2; ++cc)
#pragma unroll
        for (int rr = 0; rr < 4; ++rr) {
          float e = ex_relu_fast(ax[rt][cc][rr], ac[rt][cc][rr]);
          outa[rt][cc][rr] += gm[rt][rr] * e;
        }
  }

#pragma unroll
  for (int rt = 0; rt < 2; ++rt)
#pragma unroll
    for (int cc = 0; cc < 2; ++cc) {
      int col = bo * 64 + cw * 32 + cc * 16 + r16;
#pragma unroll
      for (int rr = 0; rr < 4; ++rr) {
        int row = row0 + rt * 16 + rr;
        if (row < N) out[(long long)row * F + col] = outa[rt][cc][rr];
      }
    }
}

extern "C" void kernel_launch(void* const* d_in, const int* in_sizes, int n_in,
                              void* d_out, int out_size, void* d_ws, size_t ws_size,
                              hipStream_t stream) {
  const float* x = (const float*)d_in[0];
  const int* edges = (const int*)d_in[1];
  const int* mask = (const int*)d_in[2];
  const float* logp = (const float*)d_in[3];
  const float* means = (const float*)d_in[4];
  const float* logvars = (const float*)d_in[5];
  const float* weight = (const float*)d_in[6];
  const float* bias = (const float*)d_in[7];
  float* out = (float*)d_out;

  int N = in_sizes[0] / F;              // 50000
  int E = in_sizes[1] / 2;              // 1600000
  int Npad = ((N + 127) / 128) * 128;   // 50048
  int RB = Npad / 64;                   // 782 row slices of 64
  int NB = N * GR;                      // bucket count
  int SB = (NB + 1023) / 1024;          // scan blocks (782 <= 1024)

  char* w = (char*)d_ws;
  auto alloc = [&](size_t bytes) {
    char* p = w;
    w += (bytes + 255) & ~(size_t)255;
    return p;
  };
  unsigned char* rec = (unsigned char*)alloc((size_t)N * RECB);
  unsigned short* xsp = (unsigned short*)alloc((size_t)Npad * F * 2);
  unsigned short* smp = (unsigned short*)alloc((size_t)Npad * F * 2);
  unsigned short* bpk = (unsigned short*)alloc((size_t)11 * F * F * 2);
  int* cnt = (int*)alloc((size_t)NB * 4);
  int* offs = (int*)alloc((size_t)(NB + 1) * 4);
  int* cur = (int*)alloc((size_t)NB * 4);
  int* bsum = (int*)alloc((size_t)1024 * 4);
  int* srclist = (int*)alloc((size_t)E * 4);
  float* degp1 = (float*)alloc((size_t)Npad * 4);
  float* gamma = (float*)alloc((size_t)KMIX * Npad * 4);
  float* ivar = (float*)alloc((size_t)KMIX * F * 4);

  kzero<<<782, 256, 0, stream>>>((unsigned int*)cnt, NB);
  k_tab<<<(KMIX * F + 255) / 256, 256, 0, stream>>>(logvars, ivar);
  k_prep<<<N, 256, 0, stream>>>(x, mask, logp, means, ivar, rec, gamma, Npad);
  k_count<<<(E + 255) / 256, 256, 0, stream>>>(edges, cnt, E);
  k_scanA<<<SB, 1024, 0, stream>>>(cnt, offs, bsum, NB);
  k_scanB<<<1, 1024, 0, stream>>>(bsum, SB);
  k_scanC<<<SB, 1024, 0, stream>>>(offs, cur, bsum, NB, E);
  k_fill<<<(E + 255) / 256, 256, 0, stream>>>(edges, cur, srclist, E);
  k_gather<<<N / 16, 1024, 0, stream>>>(rec, offs, srclist, xsp, smp, degp1);
  k_bpack<<<11 * 16 * 8, 64, 0, stream>>>(weight, means, logvars, bpk);
  int NGG = (RB + 7) / 8;
  k_gemm<<<NGG * 32, 256, 0, stream>>>(xsp, smp, bpk, degp1, gamma, bias, out, N, Npad, RB);
}

// Round 11
// 682.088 us; speedup vs baseline: 1.6660x; 1.0855x over previous
//
#include <hip/hip_runtime.h>
#include <math.h>

#define F 256
#define KMIX 5
#define RECB 640     // node record: 512 B bf16 xm + 32 B mask bits + 96 B pad
#define GR 16        // source-node groups (L2 locality phases)
#define GS 3136      // group size: 16*3136 = 50176 >= N; 3136*640 B = 2.0 MB per group

typedef __attribute__((ext_vector_type(8))) short bf16x8;
typedef __attribute__((ext_vector_type(4))) float f32x4;

__device__ __forceinline__ float bf2f(unsigned short u) {
  union { unsigned int i; float f; } v; v.i = ((unsigned int)u) << 16; return v.f;
}
__device__ __forceinline__ unsigned short f2bf(float f) {
  union { float f; unsigned int i; } v; v.f = f;
  unsigned int u = v.i;
  unsigned int r = (u + 0x7fffu + ((u >> 16) & 1u)) >> 16;
  return (unsigned short)r;
}

__device__ __forceinline__ f32x4 MFMA(bf16x8 a, bf16x8 b, f32x4 c) {
  return __builtin_amdgcn_mfma_f32_16x16x32_bf16(a, b, c, 0, 0, 0);
}

// Fast E[relu(N(mu,sigma))]: 0.5*mu + 0.5*(mu^2+c1*sig)*rsqrt(mu^2+2*c1*sig), c1=4/pi.
// Exact at w=0 and asymptotes; max abs err ~0.025*sqrt(sig). sigma==0 -> max(mu,0).
__device__ __forceinline__ float ex_relu_fast(float mu, float sig) {
  const float c1 = 1.2732395447f;
  const float c2 = 2.5464790895f;
  float t = mu * mu;
  float u = t + c1 * sig;
  float v = t + c2 * sig + 1e-20f;
  float r = __builtin_amdgcn_rsqf(v);
  return 0.5f * mu + 0.5f * u * r;
}

__global__ void kzero(unsigned int* p, long long n) {
  long long i = (long long)blockIdx.x * blockDim.x + threadIdx.x;
  long long stride = (long long)gridDim.x * blockDim.x;
  for (; i < n; i += stride) p[i] = 0u;
}

// ivar[k][f] = exp(-logvars[k][f])
__global__ __launch_bounds__(256) void k_tab(const float* __restrict__ logvars,
                                             float* __restrict__ ivar) {
  int i = blockIdx.x * 256 + threadIdx.x;
  if (i < KMIX * F) ivar[i] = __expf(-logvars[i]);
}

// Round-14 rewrite: WAVE-per-node (4 nodes / 256-block), no LDS, no barrier.
// Lane l owns features 4l..4l+3 via float4/int4 loads (was: block-per-node,
// scalar 4-B loads, __syncthreads, serial thread-0 softmax tail). Mask bits:
// lane nibble (bit j = mask[4l+j]) OR-merged across each 8-lane group with 3
// shfl_xor -> field bit 4l+j, identical layout to what k_gather's
// (mw >> ((lane&7)*4)) & 0xF consumption expects (field bits [4l, 4l+4)).
// Softmax tail runs on lane 0 of each wave: 4x more parallel, no barrier.
__global__ __launch_bounds__(256) void k_prep(
    const float* __restrict__ x, const int* __restrict__ mask,
    const float* __restrict__ logp, const float* __restrict__ means,
    const float* __restrict__ ivar,
    unsigned char* __restrict__ rec, float* __restrict__ gamma, int Npad, int N) {
  int wave = threadIdx.x >> 6, lane = threadIdx.x & 63;
  int n = blockIdx.x * 4 + wave;
  if (n >= N) return;
  int f0 = lane * 4;
  const float4 xv4 = *(const float4*)(x + (size_t)n * F + f0);
  const int4 mv4 = *(const int4*)(mask + (size_t)n * F + f0);
  float xv[4] = {xv4.x, xv4.y, xv4.z, xv4.w};
  int mv[4] = {mv4.x, mv4.y, mv4.z, mv4.w};
  unsigned char* rn = rec + (size_t)n * RECB;
  ushort4 xm;
  xm.x = mv[0] ? (unsigned short)0 : f2bf(xv[0]);
  xm.y = mv[1] ? (unsigned short)0 : f2bf(xv[1]);
  xm.z = mv[2] ? (unsigned short)0 : f2bf(xv[2]);
  xm.w = mv[3] ? (unsigned short)0 : f2bf(xv[3]);
  *(ushort4*)(rn + lane * 8) = xm;
  unsigned int nib = (mv[0] ? 1u : 0u) | (mv[1] ? 2u : 0u) |
                     (mv[2] ? 4u : 0u) | (mv[3] ? 8u : 0u);
  unsigned int wbits = nib << ((lane & 7) * 4);
  wbits |= __shfl_xor(wbits, 1, 64);
  wbits |= __shfl_xor(wbits, 2, 64);
  wbits |= __shfl_xor(wbits, 4, 64);
  if ((lane & 7) == 0) *(unsigned int*)(rn + 512 + ((lane >> 3) << 2)) = wbits;
  float lg[KMIX];
#pragma unroll
  for (int k = 0; k < KMIX; ++k) {
    const float4 mk = *(const float4*)(means + k * F + f0);
    const float4 iv = *(const float4*)(ivar + k * F + f0);
    float c = 0.0f, d;
    d = xv[0] - mk.x; c += mv[0] ? 0.0f : d * d * iv.x;
    d = xv[1] - mk.y; c += mv[1] ? 0.0f : d * d * iv.y;
    d = xv[2] - mk.z; c += mv[2] ? 0.0f : d * d * iv.z;
    d = xv[3] - mk.w; c += mv[3] ? 0.0f : d * d * iv.w;
    for (int off = 32; off > 0; off >>= 1) c += __shfl_down(c, off, 64);
    lg[k] = c;   // valid on lane 0
  }
  if (lane == 0) {
    float mx = -1e30f;
#pragma unroll
    for (int k = 0; k < KMIX; ++k) {
      lg[k] = logp[k] - 0.5f * lg[k];
      mx = fmaxf(mx, lg[k]);
    }
    float den = 0.0f, e[KMIX];
#pragma unroll
    for (int k = 0; k < KMIX; ++k) { e[k] = __expf(lg[k] - mx); den += e[k]; }
    float inv = 1.0f / den;
#pragma unroll
    for (int k = 0; k < KMIX; ++k) gamma[k * Npad + n] = e[k] * inv;
  }
}

// count per (dst, src-group) bucket
__global__ void k_count(const int* __restrict__ edges, int* __restrict__ cnt, int E) {
  int i = blockIdx.x * blockDim.x + threadIdx.x;
  if (i < E) {
    int dst = edges[E + i];
    int g = edges[i] / GS;
    atomicAdd(&cnt[dst * GR + g], 1);
  }
}

// ---- parallel exclusive scan over n = N*GR bucket counts (3 kernels) ----
__global__ __launch_bounds__(1024) void k_scanA(const int* __restrict__ cnt,
                                                int* __restrict__ excl,
                                                int* __restrict__ bsum, int n) {
  __shared__ int s[1024];
  int t = threadIdx.x;
  int i = blockIdx.x * 1024 + t;
  int v = (i < n) ? cnt[i] : 0;
  s[t] = v;
  __syncthreads();
  for (int off = 1; off < 1024; off <<= 1) {
    int u = (t >= off) ? s[t - off] : 0;
    __syncthreads();
    s[t] += u;
    __syncthreads();
  }
  if (i < n) excl[i] = s[t] - v;
  if (t == 1023) bsum[blockIdx.x] = s[1023];
}

__global__ __launch_bounds__(1024) void k_scanB(int* __restrict__ bsum, int nb) {
  __shared__ int s[1024];
  int t = threadIdx.x;
  int v = (t < nb) ? bsum[t] : 0;
  s[t] = v;
  __syncthreads();
  for (int off = 1; off < 1024; off <<= 1) {
    int u = (t >= off) ? s[t - off] : 0;
    __syncthreads();
    s[t] += u;
    __syncthreads();
  }
  if (t < nb) bsum[t] = s[t] - v;   // exclusive block offsets
}

__global__ __launch_bounds__(1024) void k_scanC(int* __restrict__ offs,
                                                int* __restrict__ cur,
                                                const int* __restrict__ bsum,
                                                int n, int E) {
  int i = blockIdx.x * 1024 + threadIdx.x;
  if (i < n) {
    int v = offs[i] + bsum[blockIdx.x];
    offs[i] = v;
    cur[i] = v;
  }
  if (i == 0) offs[n] = E;
}

__global__ void k_fill(const int* __restrict__ edges, int* __restrict__ cur,
                       int* __restrict__ srclist, int E) {
  int i = blockIdx.x * blockDim.x + threadIdx.x;
  if (i < E) {
    int src = edges[i];
    int dst = edges[E + i];
    int g = src / GS;
    int pos = atomicAdd(&cur[dst * GR + g], 1);
    srclist[pos] = src;
  }
}

// One wave per node; 16 nodes/block. srclist is group-sorted per node, so
// concurrently-running waves sweep the 16 x 2 MB record groups in near-lockstep
// -> the hot window stays L2-resident instead of thrashing to L3.
// (round-6 4-wide version: the verified-best; round-7's 8-wide regressed.)
__global__ __launch_bounds__(1024) void k_gather(
    const unsigned char* __restrict__ rec,
    const int* __restrict__ offs, const int* __restrict__ srclist,
    unsigned short* __restrict__ xs_pack, unsigned short* __restrict__ sm_pack,
    float* __restrict__ degp1) {
  __shared__ float xs_l[16][257];
  __shared__ float sm_l[16][257];
  int tile = blockIdx.x;
  int wave = threadIdx.x >> 6, lane = threadIdx.x & 63;
  int fb = lane * 4;
  int n = tile * 16 + wave;
  const unsigned char* rn = rec + (size_t)n * RECB;
  ushort4 xv = *(const ushort4*)(rn + lane * 8);
  unsigned int mw = *(const unsigned int*)(rn + 512 + ((lane >> 3) << 2));
  unsigned int nib = (mw >> ((lane & 7) * 4)) & 0xFu;
  unsigned int macc = (nib | (nib << 7) | (nib << 14) | (nib << 21)) & 0x01010101u;
  float a0 = bf2f(xv.x), a1 = bf2f(xv.y), a2 = bf2f(xv.z), a3 = bf2f(xv.w);
  int s0 = offs[n * GR], s1 = offs[n * GR + GR];   // contiguous across groups
  int i = s0;
  int nsa = 0, nsb = 0, nsc = 0, nsd = 0;
  if (i + 4 <= s1) {
    nsa = srclist[i]; nsb = srclist[i + 1]; nsc = srclist[i + 2]; nsd = srclist[i + 3];
  }
  while (i + 4 <= s1) {
    int sa = nsa, sb = nsb, sc = nsc, sd = nsd;
    const unsigned char* ra = rec + (size_t)sa * RECB;
    const unsigned char* rb = rec + (size_t)sb * RECB;
    const unsigned char* rc = rec + (size_t)sc * RECB;
    const unsigned char* rd = rec + (size_t)sd * RECB;
    ushort4 va = *(const ushort4*)(ra + lane * 8);
    ushort4 vb = *(const ushort4*)(rb + lane * 8);
    ushort4 vc = *(const ushort4*)(rc + lane * 8);
    ushort4 vd = *(const ushort4*)(rd + lane * 8);
    unsigned int wa = *(const unsigned int*)(ra + 512 + ((lane >> 3) << 2));
    unsigned int wb = *(const unsigned int*)(rb + 512 + ((lane >> 3) << 2));
    unsigned int wc = *(const unsigned int*)(rc + 512 + ((lane >> 3) << 2));
    unsigned int wd = *(const unsigned int*)(rd + 512 + ((lane >> 3) << 2));
    i += 4;
    if (i + 4 <= s1) {   // prefetch next indices before waiting on the gathers
      nsa = srclist[i]; nsb = srclist[i + 1]; nsc = srclist[i + 2]; nsd = srclist[i + 3];
    }
    a0 += bf2f(va.x) + bf2f(vb.x) + bf2f(vc.x) + bf2f(vd.x);
    a1 += bf2f(va.y) + bf2f(vb.y) + bf2f(vc.y) + bf2f(vd.y);
    a2 += bf2f(va.z) + bf2f(vb.z) + bf2f(vc.z) + bf2f(vd.z);
    a3 += bf2f(va.w) + bf2f(vb.w) + bf2f(vc.w) + bf2f(vd.w);
    unsigned int na = (wa >> ((lane & 7) * 4)) & 0xFu;
    unsigned int nb = (wb >> ((lane & 7) * 4)) & 0xFu;
    unsigned int nc = (wc >> ((lane & 7) * 4)) & 0xFu;
    unsigned int nd = (wd >> ((lane & 7) * 4)) & 0xFu;
    macc += (na | (na << 7) | (na << 14) | (na << 21)) & 0x01010101u;
    macc += (nb | (nb << 7) | (nb << 14) | (nb << 21)) & 0x01010101u;
    macc += (nc | (nc << 7) | (nc << 14) | (nc << 21)) & 0x01010101u;
    macc += (nd | (nd << 7) | (nd << 14) | (nd << 21)) & 0x01010101u;
  }
  for (; i < s1; ++i) {
    int s = srclist[i];
    const unsigned char* rs = rec + (size_t)s * RECB;
    ushort4 sv = *(const ushort4*)(rs + lane * 8);
    unsigned int ws = *(const unsigned int*)(rs + 512 + ((lane >> 3) << 2));
    a0 += bf2f(sv.x); a1 += bf2f(sv.y); a2 += bf2f(sv.z); a3 += bf2f(sv.w);
    unsigned int ns = (ws >> ((lane & 7) * 4)) & 0xFu;
    macc += (ns | (ns << 7) | (ns << 14) | (ns << 21)) & 0x01010101u;
  }
  xs_l[wave][fb] = a0; xs_l[wave][fb + 1] = a1; xs_l[wave][fb + 2] = a2; xs_l[wave][fb + 3] = a3;
  sm_l[wave][fb] = (float)(macc & 0xFFu);
  sm_l[wave][fb + 1] = (float)((macc >> 8) & 0xFFu);
  sm_l[wave][fb + 2] = (float)((macc >> 16) & 0xFFu);
  sm_l[wave][fb + 3] = (float)(macc >> 24);
  if (lane == 0) degp1[n] = (float)(s1 - s0 + 1);
  __syncthreads();
  if (threadIdx.x < 512) {
    int slot = threadIdx.x;
    int kt = slot >> 6, l = slot & 63;
    int r = l & 15, q = l >> 4;
    int fbase = kt * 32 + q * 8;
    bf16x8 vx, vs;
#pragma unroll
    for (int j = 0; j < 8; ++j) {
      vx[j] = (short)f2bf(xs_l[r][fbase + j]);
      vs[j] = (short)f2bf(sm_l[r][fbase + j]);
    }
    long long po = ((long long)tile * 8 + kt) * 64 + l;
    ((bf16x8*)xs_pack)[po] = vx;
    ((bf16x8*)sm_pack)[po] = vs;
  }
}

// Pack B-matrices in MFMA B-fragment order.
// Layout (bf16x8 units): [0, 8192): W as [ot][kt][lane].
// [8192, ...): paired k-matrices: (((k*16+ot)*8+kt)*64+lane)*2 + s,
//   s=0: means_k*W fragment, s=1: var_k*W^2 fragment. Each lane's (bw,bv)
//   pair is 32 B contiguous -> one address base, bv always L1-hits behind bw.
__global__ __launch_bounds__(64) void k_bpack(
    const float* __restrict__ weight, const float* __restrict__ means,
    const float* __restrict__ logvars, unsigned short* __restrict__ bpack) {
  int bid = blockIdx.x;
  int kt = bid & 7, ot = (bid >> 3) & 15, m = bid >> 7;
  int l = threadIdx.x;
  int r = l & 15, q = l >> 4;
  int o = ot * 16 + r;
  bf16x8 v;
#pragma unroll
  for (int j = 0; j < 8; ++j) {
    int f = kt * 32 + q * 8 + j;
    float wv = weight[f * F + o];
    float val;
    if (m == 0) val = wv;
    else if (m <= 5) val = means[(m - 1) * F + f] * wv;
    else val = __expf(logvars[(m - 6) * F + f]) * wv * wv;
    v[j] = (short)f2bf(val);
  }
  size_t idx;
  if (m == 0) {
    idx = ((size_t)ot * 8 + kt) * 64 + l;
  } else {
    int s = (m <= 5) ? 0 : 1;
    int k = (m <= 5) ? (m - 1) : (m - 6);
    idx = 8192 + ((((size_t)k * 16 + ot) * 8 + kt) * 64 + l) * 2 + s;
  }
  ((bf16x8*)bpack)[idx] = v;
}

// Fused GEMM + ex_relu + gamma-weighted k-reduction.
// VERIFIED BEST (r10: 177 us, MfmaUtil 16.7, FETCH 70 MB): 2x2-reuse waves,
// (256,3), bias fold, runtime k-loop, paired (bw,bv) fragments.
// Closed levers (do not reopen): launch_bounds (256,4) spilled twice (r1,r5);
// k-loop unroll spilled at 5x (r7) AND 2x (r8) — body sits ~148/170 regs.
__global__ __launch_bounds__(256, 3) void k_gemm(
    const unsigned short* __restrict__ xs_pack, const unsigned short* __restrict__ sm_pack,
    const unsigned short* __restrict__ bpack, const float* __restrict__ degp1,
    const float* __restrict__ gamma, const float* __restrict__ bias,
    float* __restrict__ out, int N, int Npad, int RB) {
  int L = blockIdx.x;
  int rb = (L >> 5) * 8 + (L & 7);     // 64-row slice; L%8 -> XCD (4 bo of one rb share XCD)
  int bo = (L >> 3) & 3;               // 64-col block
  if (rb >= RB) return;
  __shared__ unsigned char sp_lds[32768];
  int tid = threadIdx.x;
  int wave = tid >> 6, lane = tid & 63;
  int rw = wave >> 1, cw = wave & 1;   // row-wave, col-wave
  int q = lane >> 4, r16 = lane & 15;
  int rt0 = rb * 4 + rw * 2;           // first 16-row tile of this wave
  int ct0 = bo * 4 + cw * 2;           // first 16-col tile of this wave
  const bf16x8* XP = (const bf16x8*)xs_pack;
  const bf16x8* BP = (const bf16x8*)bpack;
  const bf16x8* BPp = BP + 8192;       // paired (w,v) region

  // cooperative stage: SP slice for rows [rb*64, +64) -> LDS (32 KB)
  {
    const uint4* src = (const uint4*)((const unsigned char*)sm_pack + (size_t)rb * 32768) + tid;
    uint4* dst = (uint4*)(void*)sp_lds + tid;
#pragma unroll
    for (int it = 0; it < 8; ++it) dst[it * 256] = src[it * 256];
  }

  // C1 = xs @ W (shared across all k) — overlaps LDS staging
  f32x4 C1[2][2];
#pragma unroll
  for (int rt = 0; rt < 2; ++rt)
#pragma unroll
    for (int cc = 0; cc < 2; ++cc) C1[rt][cc] = (f32x4){0.f, 0.f, 0.f, 0.f};
#pragma unroll
  for (int kt = 0; kt < 8; ++kt) {
    bf16x8 a0 = XP[((size_t)rt0 * 8 + kt) * 64 + lane];
    bf16x8 a1 = XP[((size_t)(rt0 + 1) * 8 + kt) * 64 + lane];
#pragma unroll
    for (int cc = 0; cc < 2; ++cc) {
      bf16x8 b = BP[((size_t)(ct0 + cc) * 8 + kt) * 64 + lane];
      C1[0][cc] = MFMA(a0, b, C1[0][cc]);
      C1[1][cc] = MFMA(a1, b, C1[1][cc]);
    }
  }

  int row0 = rb * 64 + rw * 32 + q * 4;
  // fold deg*bias into C1: mu_k = C1' + sum_kt sp.bw_k  (dp/bs dead after this)
  {
    float dp[2][4];
#pragma unroll
    for (int rt = 0; rt < 2; ++rt)
#pragma unroll
      for (int rr = 0; rr < 4; ++rr) dp[rt][rr] = degp1[row0 + rt * 16 + rr];
    float bs[2];
#pragma unroll
    for (int cc = 0; cc < 2; ++cc) bs[cc] = bias[bo * 64 + cw * 32 + cc * 16 + r16];
#pragma unroll
    for (int rt = 0; rt < 2; ++rt)
#pragma unroll
      for (int cc = 0; cc < 2; ++cc)
#pragma unroll
        for (int rr = 0; rr < 4; ++rr) C1[rt][cc][rr] += dp[rt][rr] * bs[cc];
  }

  f32x4 outa[2][2];
#pragma unroll
  for (int rt = 0; rt < 2; ++rt)
#pragma unroll
    for (int cc = 0; cc < 2; ++cc) outa[rt][cc] = (f32x4){0.f, 0.f, 0.f, 0.f};

  __syncthreads();
  const unsigned char* myl = sp_lds + rw * 16384;   // this row-wave's 32-row SP slice

  for (int k = 0; k < KMIX; ++k) {
    float gm[2][4];
#pragma unroll
    for (int rt = 0; rt < 2; ++rt)
#pragma unroll
      for (int rr = 0; rr < 4; ++rr) gm[rt][rr] = gamma[k * Npad + row0 + rt * 16 + rr];
    f32x4 ax[2][2], ac[2][2];
#pragma unroll
    for (int rt = 0; rt < 2; ++rt)
#pragma unroll
      for (int cc = 0; cc < 2; ++cc) {
        ax[rt][cc] = C1[rt][cc];
        ac[rt][cc] = (f32x4){0.f, 0.f, 0.f, 0.f};
      }
#pragma unroll
    for (int kt = 0; kt < 8; ++kt) {
      bf16x8 sp0 = *(const bf16x8*)(myl + kt * 1024 + lane * 16);
      bf16x8 sp1 = *(const bf16x8*)(myl + 8192 + kt * 1024 + lane * 16);
#pragma unroll
      for (int cc = 0; cc < 2; ++cc) {
        int c = ct0 + cc;
        const bf16x8* pp = &BPp[((((size_t)k * 16 + c) * 8 + kt) * 64 + lane) * 2];
        bf16x8 bw = pp[0];
        bf16x8 bv = pp[1];
        ax[0][cc] = MFMA(sp0, bw, ax[0][cc]);
        ax[1][cc] = MFMA(sp1, bw, ax[1][cc]);
        ac[0][cc] = MFMA(sp0, bv, ac[0][cc]);
        ac[1][cc] = MFMA(sp1, bv, ac[1][cc]);
      }
    }
#pragma unroll
    for (int rt = 0; rt < 2; ++rt)
#pragma unroll
      for (int cc = 0; cc < 2; ++cc)
#pragma unroll
        for (int rr = 0; rr < 4; ++rr) {
          float e = ex_relu_fast(ax[rt][cc][rr], ac[rt][cc][rr]);
          outa[rt][cc][rr] += gm[rt][rr] * e;
        }
  }

#pragma unroll
  for (int rt = 0; rt < 2; ++rt)
#pragma unroll
    for (int cc = 0; cc < 2; ++cc) {
      int col = bo * 64 + cw * 32 + cc * 16 + r16;
#pragma unroll
      for (int rr = 0; rr < 4; ++rr) {
        int row = row0 + rt * 16 + rr;
        if (row < N) out[(long long)row * F + col] = outa[rt][cc][rr];
      }
    }
}

extern "C" void kernel_launch(void* const* d_in, const int* in_sizes, int n_in,
                              void* d_out, int out_size, void* d_ws, size_t ws_size,
                              hipStream_t stream) {
  const float* x = (const float*)d_in[0];
  const int* edges = (const int*)d_in[1];
  const int* mask = (const int*)d_in[2];
  const float* logp = (const float*)d_in[3];
  const float* means = (const float*)d_in[4];
  const float* logvars = (const float*)d_in[5];
  const float* weight = (const float*)d_in[6];
  const float* bias = (const float*)d_in[7];
  float* out = (float*)d_out;

  int N = in_sizes[0] / F;              // 50000
  int E = in_sizes[1] / 2;              // 1600000
  int Npad = ((N + 127) / 128) * 128;   // 50048
  int RB = Npad / 64;                   // 782 row slices of 64
  int NB = N * GR;                      // bucket count
  int SB = (NB + 1023) / 1024;          // scan blocks (782 <= 1024)

  char* w = (char*)d_ws;
  auto alloc = [&](size_t bytes) {
    char* p = w;
    w += (bytes + 255) & ~(size_t)255;
    return p;
  };
  unsigned char* rec = (unsigned char*)alloc((size_t)N * RECB);
  unsigned short* xsp = (unsigned short*)alloc((size_t)Npad * F * 2);
  unsigned short* smp = (unsigned short*)alloc((size_t)Npad * F * 2);
  unsigned short* bpk = (unsigned short*)alloc((size_t)11 * F * F * 2);
  int* cnt = (int*)alloc((size_t)NB * 4);
  int* offs = (int*)alloc((size_t)(NB + 1) * 4);
  int* cur = (int*)alloc((size_t)NB * 4);
  int* bsum = (int*)alloc((size_t)1024 * 4);
  int* srclist = (int*)alloc((size_t)E * 4);
  float* degp1 = (float*)alloc((size_t)Npad * 4);
  float* gamma = (float*)alloc((size_t)KMIX * Npad * 4);
  float* ivar = (float*)alloc((size_t)KMIX * F * 4);

  kzero<<<782, 256, 0, stream>>>((unsigned int*)cnt, NB);
  k_tab<<<(KMIX * F + 255) / 256, 256, 0, stream>>>(logvars, ivar);
  k_prep<<<(N + 3) / 4, 256, 0, stream>>>(x, mask, logp, means, ivar, rec, gamma, Npad, N);
  k_count<<<(E + 255) / 256, 256, 0, stream>>>(edges, cnt, E);
  k_scanA<<<SB, 1024, 0, stream>>>(cnt, offs, bsum, NB);
  k_scanB<<<1, 1024, 0, stream>>>(bsum, SB);
  k_scanC<<<SB, 1024, 0, stream>>>(offs, cur, bsum, NB, E);
  k_fill<<<(E + 255) / 256, 256, 0, stream>>>(edges, cur, srclist, E);
  k_gather<<<N / 16, 1024, 0, stream>>>(rec, offs, srclist, xsp, smp, degp1);
  k_bpack<<<11 * 16 * 8, 64, 0, stream>>>(weight, means, logvars, bpk);
  int NGG = (RB + 7) / 8;
  k_gemm<<<NGG * 32, 256, 0, stream>>>(xsp, smp, bpk, degp1, gamma, bias, out, N, Npad, RB);
}